// Round 3
// baseline (11435.602 us; speedup 1.0000x reference)
//
#include <hip/hip_runtime.h>
#include <hip/hip_bf16.h>
#include <cstdint>
#include <cstddef>

// Problem sizes (fixed)
#define BB 64
#define SS 1024
#define II 1024
#define HH 1024
#define G3 3072   // 3*HH

typedef float  f32x4  __attribute__((ext_vector_type(4)));
typedef short  bf16x8 __attribute__((ext_vector_type(8)));

__device__ __forceinline__ unsigned short f2b(float f) {
    unsigned u = __float_as_uint(f);
    u += 0x7FFFu + ((u >> 16) & 1u);   // RNE
    return (unsigned short)(u >> 16);
}
__device__ __forceinline__ float b2f(unsigned short s) {
    return __uint_as_float(((unsigned)s) << 16);
}

// Interleaved h-slab layout (per 16-batch group, j = hidden index 0..1023):
//   elem offset F(b,j) = (j>>3)*128 + b*8 + (j&7)     (16K bf16 = 32KB slab)
// Consumer wave w, lane l, chunk kc reads 16B at byte offset
//   (w*32 + kc*4 + (l>>4))*256 + (l&15)*16            -> 1KB contiguous per wave-load.

// ---------------------------------------------------------------------------
// Kernel 1: gi = x @ W_ih^T + b_ih      (M=B*S=65536, K=1024, N=3072)
// ---------------------------------------------------------------------------
template<int GI_BF16>
__global__ __launch_bounds__(256)
void gi_gemm(const float* __restrict__ X, const float* __restrict__ W,
             const float* __restrict__ bias, void* __restrict__ gi_out)
{
    __shared__ short As[128][40];   // +8 pad breaks bank conflicts
    __shared__ short Bs[128][40];

    const int t    = threadIdx.x;
    const int lane = t & 63;
    const int wave = t >> 6;
    const int m0   = blockIdx.y * 128;
    const int n0   = blockIdx.x * 128;

    f32x4 acc[4][4] = {};

    for (int k0 = 0; k0 < II; k0 += 32) {
        __syncthreads();
        #pragma unroll
        for (int q = 0; q < 4; ++q) {
            int row = (t >> 3) + 32 * q;
            int col = (t & 7) * 4;
            const float4 a = *reinterpret_cast<const float4*>(X + (size_t)(m0 + row) * II + k0 + col);
            const float4 b = *reinterpret_cast<const float4*>(W + (size_t)(n0 + row) * II + k0 + col);
            As[row][col + 0] = (short)f2b(a.x); As[row][col + 1] = (short)f2b(a.y);
            As[row][col + 2] = (short)f2b(a.z); As[row][col + 3] = (short)f2b(a.w);
            Bs[row][col + 0] = (short)f2b(b.x); Bs[row][col + 1] = (short)f2b(b.y);
            Bs[row][col + 2] = (short)f2b(b.z); Bs[row][col + 3] = (short)f2b(b.w);
        }
        __syncthreads();

        const int mb = (wave & 1) * 64;
        const int nb = (wave >> 1) * 64;
        bf16x8 af[4], bf[4];
        #pragma unroll
        for (int i = 0; i < 4; ++i) {
            af[i] = *reinterpret_cast<const bf16x8*>(&As[mb + i * 16 + (lane & 15)][(lane >> 4) * 8]);
            bf[i] = *reinterpret_cast<const bf16x8*>(&Bs[nb + i * 16 + (lane & 15)][(lane >> 4) * 8]);
        }
        #pragma unroll
        for (int mi = 0; mi < 4; ++mi)
            #pragma unroll
            for (int ni = 0; ni < 4; ++ni)
                acc[mi][ni] = __builtin_amdgcn_mfma_f32_16x16x32_bf16(af[mi], bf[ni], acc[mi][ni], 0, 0, 0);
    }

    const int mb = (wave & 1) * 64;
    const int nb = (wave >> 1) * 64;
    #pragma unroll
    for (int ni = 0; ni < 4; ++ni) {
        int ncol = n0 + nb + ni * 16 + (lane & 15);
        float bv = bias[ncol];
        #pragma unroll
        for (int mi = 0; mi < 4; ++mi) {
            int mrow = m0 + mb + mi * 16 + ((lane >> 4) << 2);
            #pragma unroll
            for (int e = 0; e < 4; ++e) {
                float v = acc[mi][ni][e] + bv;
                size_t idx = (size_t)(mrow + e) * G3 + ncol;
                if (GI_BF16) ((unsigned short*)gi_out)[idx] = f2b(v);
                else         ((float*)gi_out)[idx] = v;
            }
        }
    }
}

// ---------------------------------------------------------------------------
// Kernel 2: init  (reset flags, h16[buf0] = bf16(h0) in interleaved layout)
// ---------------------------------------------------------------------------
__global__ __launch_bounds__(256)
void gru_init(const float* __restrict__ h0, unsigned short* __restrict__ h16,
              int* __restrict__ flags)
{
    int i = blockIdx.x * 256 + threadIdx.x;   // i = b*1024 + j, 65536 total
    int b = i >> 10, j = i & 1023;
    int dst = (b >> 4) * 16384 + (j >> 3) * 128 + (b & 15) * 8 + (j & 7);
    h16[dst] = f2b(h0[i]);
    if (i < 256) flags[i] = 0;
}

// ---------------------------------------------------------------------------
// Kernel 3: sequential scan. Cooperative, 256 blocks x 256 threads.
// group = bid&3 (16 batches; note bid%8 -> XCD, so each XCD hosts ONE group
// and its L2 dedups the group's h broadcast), jb = bid>>2 (16 j-cols).
// Producers publish h via sc1 (write-through) relaxed-agent stores; consumers
// do one agent-acquire (s_waitcnt + buffer_inv) per step, then plain CACHED
// loads of the interleaved slab -> L2 hits for 31/32 blocks per XCD.
// ---------------------------------------------------------------------------
template<int GI_BF16>
__global__ __launch_bounds__(256)
void gru_scan(const void* __restrict__ gi_v, const float* __restrict__ Whh,
              const float* __restrict__ h0, unsigned short* __restrict__ h16,
              int* __restrict__ flags, float* __restrict__ out)
{
    const int t     = threadIdx.x;
    const int lane  = t & 63;
    const int wave  = t >> 6;
    const int bid   = blockIdx.x;
    const int group = bid & 3;
    const int jb    = bid >> 2;

    __shared__ f32x4 part[4][3][64];  // [wave][gate][lane]

    // ---- one-time: preload W_hh slice as MFMA B-fragments (96 VGPR) ----
    bf16x8 wf[8][3];
    #pragma unroll
    for (int kc = 0; kc < 8; ++kc) {
        #pragma unroll
        for (int nt = 0; nt < 3; ++nt) {
            int rowg = nt * HH + jb * 16 + (lane & 15);
            int k    = wave * 256 + kc * 32 + ((lane >> 4) << 3);
            const float4* src = reinterpret_cast<const float4*>(Whh + (size_t)rowg * HH + k);
            float4 f0 = src[0], f1 = src[1];
            bf16x8 w;
            w[0] = (short)f2b(f0.x); w[1] = (short)f2b(f0.y);
            w[2] = (short)f2b(f0.z); w[3] = (short)f2b(f0.w);
            w[4] = (short)f2b(f1.x); w[5] = (short)f2b(f1.y);
            w[6] = (short)f2b(f1.z); w[7] = (short)f2b(f1.w);
            wf[kc][nt] = w;
        }
    }

    const int b_l = t >> 4, j_l = t & 15;
    const int b_g = (group << 4) + b_l;
    const int j_g = (jb << 4) + j_l;
    float hreg = h0[b_g * HH + j_g];

    // consumer A-frag byte offset within slab (add kc<<10 per chunk)
    const int cons_base = ((wave * 32 + (lane >> 4)) << 8) + ((lane & 15) << 4);
    // producer packed-pair byte offset within slab (even j_l threads)
    const int prod_off  = ((j_g >> 3) << 8) + (b_l << 4) + ((j_g & 7) << 1);

    for (int s = 0; s < SS; ++s) {
        const int p = s & 1;
        const unsigned short* rslab = h16 + p * 65536 + group * 16384;
        unsigned short*       wslab = h16 + (p ^ 1) * 65536 + group * 16384;

        // prefetch gi (independent of h — issues before the poll)
        size_t gib = ((size_t)b_g * SS + s) * G3;
        float ir, iz, inn;
        if (GI_BF16) {
            const unsigned short* g16 = (const unsigned short*)gi_v;
            ir  = b2f(g16[gib + j_g]);
            iz  = b2f(g16[gib + HH + j_g]);
            inn = b2f(g16[gib + 2 * HH + j_g]);
        } else {
            const float* g32 = (const float*)gi_v;
            ir  = g32[gib + j_g];
            iz  = g32[gib + HH + j_g];
            inn = g32[gib + 2 * HH + j_g];
        }

        if (s > 0) {
            if (wave == 0) {
                const int idx = (group << 6) | lane;   // 64 flags, one per lane
                while (true) {
                    int v = __hip_atomic_load(&flags[idx], __ATOMIC_RELAXED,
                                              __HIP_MEMORY_SCOPE_AGENT);
                    if (__all(v >= s)) break;
                }
            }
            __syncthreads();
            // agent acquire: s_waitcnt + buffer_inv (L1+L2) — per wave, so each
            // wave's subsequent cached loads are ordered after its own inv.
            (void)__hip_atomic_load(&flags[group << 6], __ATOMIC_ACQUIRE,
                                    __HIP_MEMORY_SCOPE_AGENT);
        }

        // ---- load this wave's h A-fragments: 8 x contiguous 1KB cached loads
        bf16x8 af[8];
        const char* rb = (const char*)rslab + cons_base;
        #pragma unroll
        for (int kc = 0; kc < 8; ++kc)
            af[kc] = *reinterpret_cast<const bf16x8*>(rb + (kc << 10));

        // ---- gh = h @ W_hh^T (48 cols), K split over waves ----
        f32x4 a0 = {0,0,0,0}, a1 = {0,0,0,0}, a2 = {0,0,0,0};
        #pragma unroll
        for (int kc = 0; kc < 8; ++kc) {
            a0 = __builtin_amdgcn_mfma_f32_16x16x32_bf16(af[kc], wf[kc][0], a0, 0, 0, 0);
            a1 = __builtin_amdgcn_mfma_f32_16x16x32_bf16(af[kc], wf[kc][1], a1, 0, 0, 0);
            a2 = __builtin_amdgcn_mfma_f32_16x16x32_bf16(af[kc], wf[kc][2], a2, 0, 0, 0);
        }
        part[wave][0][lane] = a0;
        part[wave][1][lane] = a1;
        part[wave][2][lane] = a2;
        __syncthreads();

        // ---- cross-wave K reduce merged with gates ----
        const int lp = ((b_l >> 2) << 4) | j_l;
        const int e  = b_l & 3;
        float hr = 0.f, hz = 0.f, hn = 0.f;
        #pragma unroll
        for (int w = 0; w < 4; ++w) {
            hr += part[w][0][lp][e];
            hz += part[w][1][lp][e];
            hn += part[w][2][lp][e];
        }

        // fast gates: sigmoid/tanh via v_exp + v_rcp (saturate correctly)
        float r  = __builtin_amdgcn_rcpf(1.f + __expf(-(ir + hr)));
        float z  = __builtin_amdgcn_rcpf(1.f + __expf(-(iz + hz)));
        float e2 = __expf(2.f * (inn + r * hn));
        float n  = 1.f - 2.f * __builtin_amdgcn_rcpf(e2 + 1.f);
        float hnew = (1.f - z) * n + z * hreg;
        hreg = hnew;

        // ---- publish h (packed bf16 pair, relaxed agent / sc1 write-through)
        unsigned short myb = f2b(hnew);
        unsigned pv = (unsigned)__shfl_xor((int)(unsigned)myb, 1);
        if (!(j_l & 1)) {
            unsigned val = ((unsigned)myb) | (pv << 16);
            __hip_atomic_store((unsigned*)((char*)wslab + prod_off), val,
                               __ATOMIC_RELAXED, __HIP_MEMORY_SCOPE_AGENT);
        }

        // release: drain h16 stores to coherence point, then one flag store
        asm volatile("s_waitcnt vmcnt(0)" ::: "memory");
        __syncthreads();
        if (t == 0)
            __hip_atomic_store(&flags[(group << 6) | jb], s + 1,
                               __ATOMIC_RELAXED, __HIP_MEMORY_SCOPE_AGENT);

        // out store AFTER the release — not part of the recurrence
        out[((size_t)b_g * SS + s) * HH + j_g] = hnew;
    }

    out[(size_t)BB * SS * HH + (size_t)b_g * HH + j_g] = hreg;
}

// ---------------------------------------------------------------------------
// Host launcher
// ---------------------------------------------------------------------------
extern "C" void kernel_launch(void* const* d_in, const int* in_sizes, int n_in,
                              void* d_out, int out_size, void* d_ws, size_t ws_size,
                              hipStream_t stream)
{
    const float* x   = (const float*)d_in[0];
    const float* h0  = (const float*)d_in[1];
    const float* Wih = (const float*)d_in[2];
    const float* Whh = (const float*)d_in[3];
    const float* bih = (const float*)d_in[4];
    float* out = (float*)d_out;

    char* ws = (char*)d_ws;
    unsigned short* h16 = (unsigned short*)ws;               // 2 * 64KiB slabs * 2 = 256 KiB
    int* flags          = (int*)(ws + 262144);               // 256 * 4B
    void* gi            = (void*)(ws + (1 << 20));           // 1 MiB offset

    const size_t gi32_bytes = (size_t)BB * SS * G3 * 4;      // 768 MiB
    const size_t gi16_bytes = gi32_bytes / 2;                // 384 MiB
    const bool use_f32 = ws_size >= ((size_t)(1 << 20) + gi32_bytes);
    const bool use_b16 = !use_f32 && ws_size >= ((size_t)(1 << 20) + gi16_bytes);
    if (!use_f32 && !use_b16) return;

    gru_init<<<dim3(256), dim3(256), 0, stream>>>(h0, h16, flags);

    const void* gi_c = gi;
    const float* Whh_c = Whh;
    const float* h0_c = h0;
    unsigned short* h16_c = h16;
    int* flags_c = flags;
    float* out_c = out;
    void* args[] = { (void*)&gi_c, (void*)&Whh_c, (void*)&h0_c,
                     (void*)&h16_c, (void*)&flags_c, (void*)&out_c };

    if (use_f32) {
        gi_gemm<0><<<dim3(24, 512), dim3(256), 0, stream>>>(x, Wih, bih, gi);
        hipLaunchCooperativeKernel((const void*)&gru_scan<0>, dim3(256), dim3(256),
                                   args, 0, stream);
    } else {
        gi_gemm<1><<<dim3(24, 512), dim3(256), 0, stream>>>(x, Wih, bih, gi);
        hipLaunchCooperativeKernel((const void*)&gru_scan<1>, dim3(256), dim3(256),
                                   args, 0, stream);
    }
}

// Round 4
// 4376.102 us; speedup vs baseline: 2.6132x; 2.6132x over previous
//
#include <hip/hip_runtime.h>
#include <hip/hip_bf16.h>
#include <cstdint>
#include <cstddef>

// Problem sizes (fixed)
#define BB 64
#define SS 1024
#define II 1024
#define HH 1024
#define G3 3072   // 3*HH

typedef float  f32x4  __attribute__((ext_vector_type(4)));
typedef short  bf16x8 __attribute__((ext_vector_type(8)));

__device__ __forceinline__ unsigned short f2b(float f) {
    unsigned u = __float_as_uint(f);
    u += 0x7FFFu + ((u >> 16) & 1u);   // RNE
    return (unsigned short)(u >> 16);
}
__device__ __forceinline__ float b2f(unsigned short s) {
    return __uint_as_float(((unsigned)s) << 16);
}

// Interleaved h-slab layout (per 16-batch group, j = hidden index 0..1023):
//   elem offset F(b,j) = (j>>3)*128 + b*8 + (j&7)     (16K bf16 = 32KB slab)
// A wave's MFMA A-fragment (16 batches x 8 k) is 16B-contiguous per lane and
// 1KB-contiguous per wave -> conflict-free LDS reads after staging.

// ---------------------------------------------------------------------------
// Kernel 1: gi = x @ W_ih^T + b_ih      (M=B*S=65536, K=1024, N=3072)
// ---------------------------------------------------------------------------
template<int GI_BF16>
__global__ __launch_bounds__(256)
void gi_gemm(const float* __restrict__ X, const float* __restrict__ W,
             const float* __restrict__ bias, void* __restrict__ gi_out)
{
    __shared__ short As[128][40];   // +8 pad breaks bank conflicts
    __shared__ short Bs[128][40];

    const int t    = threadIdx.x;
    const int lane = t & 63;
    const int wave = t >> 6;
    const int m0   = blockIdx.y * 128;
    const int n0   = blockIdx.x * 128;

    f32x4 acc[4][4] = {};

    for (int k0 = 0; k0 < II; k0 += 32) {
        __syncthreads();
        #pragma unroll
        for (int q = 0; q < 4; ++q) {
            int row = (t >> 3) + 32 * q;
            int col = (t & 7) * 4;
            const float4 a = *reinterpret_cast<const float4*>(X + (size_t)(m0 + row) * II + k0 + col);
            const float4 b = *reinterpret_cast<const float4*>(W + (size_t)(n0 + row) * II + k0 + col);
            As[row][col + 0] = (short)f2b(a.x); As[row][col + 1] = (short)f2b(a.y);
            As[row][col + 2] = (short)f2b(a.z); As[row][col + 3] = (short)f2b(a.w);
            Bs[row][col + 0] = (short)f2b(b.x); Bs[row][col + 1] = (short)f2b(b.y);
            Bs[row][col + 2] = (short)f2b(b.z); Bs[row][col + 3] = (short)f2b(b.w);
        }
        __syncthreads();

        const int mb = (wave & 1) * 64;
        const int nb = (wave >> 1) * 64;
        bf16x8 af[4], bf[4];
        #pragma unroll
        for (int i = 0; i < 4; ++i) {
            af[i] = *reinterpret_cast<const bf16x8*>(&As[mb + i * 16 + (lane & 15)][(lane >> 4) * 8]);
            bf[i] = *reinterpret_cast<const bf16x8*>(&Bs[nb + i * 16 + (lane & 15)][(lane >> 4) * 8]);
        }
        #pragma unroll
        for (int mi = 0; mi < 4; ++mi)
            #pragma unroll
            for (int ni = 0; ni < 4; ++ni)
                acc[mi][ni] = __builtin_amdgcn_mfma_f32_16x16x32_bf16(af[mi], bf[ni], acc[mi][ni], 0, 0, 0);
    }

    const int mb = (wave & 1) * 64;
    const int nb = (wave >> 1) * 64;
    #pragma unroll
    for (int ni = 0; ni < 4; ++ni) {
        int ncol = n0 + nb + ni * 16 + (lane & 15);
        float bv = bias[ncol];
        #pragma unroll
        for (int mi = 0; mi < 4; ++mi) {
            int mrow = m0 + mb + mi * 16 + ((lane >> 4) << 2);
            #pragma unroll
            for (int e = 0; e < 4; ++e) {
                float v = acc[mi][ni][e] + bv;
                size_t idx = (size_t)(mrow + e) * G3 + ncol;
                if (GI_BF16) ((unsigned short*)gi_out)[idx] = f2b(v);
                else         ((float*)gi_out)[idx] = v;
            }
        }
    }
}

// ---------------------------------------------------------------------------
// Kernel 2: init  (reset flags, h16[buf0] = bf16(h0) in interleaved layout)
// ---------------------------------------------------------------------------
__global__ __launch_bounds__(256)
void gru_init(const float* __restrict__ h0, unsigned short* __restrict__ h16,
              int* __restrict__ flags)
{
    int i = blockIdx.x * 256 + threadIdx.x;   // i = b*1024 + j, 65536 total
    int b = i >> 10, j = i & 1023;
    int dst = (b >> 4) * 16384 + (j >> 3) * 128 + (b & 15) * 8 + (j & 7);
    h16[dst] = f2b(h0[i]);
    if (i < 2048) flags[i] = 0;   // 128 flags at 16-int (64B) stride
}

// ---------------------------------------------------------------------------
// Kernel 3: sequential scan. Cooperative, 128 blocks x 512 threads (8 waves).
// group = bid&3 (16 batches), jb = bid>>2 (32 j-blocks of 32 j each).
// Wave w: kg = w&3 (K-slice of 256), ng = w>>2 (16-j sub-block).
// Per step: stage group's 32KB h-slab to LDS (8B sc1 loads, wave-contiguous),
// MFMA M=16,N=48,K=256 per wave from LDS, cross-wave K-reduce via LDS,
// gates fp32, publish via sc1 stores, vmcnt(0) release, padded flags.
// NO cache-maintenance ops (acquire/buffer_inv) anywhere in the loop.
// ---------------------------------------------------------------------------
template<int GI_BF16>
__global__ __launch_bounds__(512, 2)
void gru_scan(const void* __restrict__ gi_v, const float* __restrict__ Whh,
              const float* __restrict__ h0, unsigned short* __restrict__ h16,
              int* __restrict__ flags, float* __restrict__ out)
{
    const int t     = threadIdx.x;
    const int lane  = t & 63;
    const int wave  = t >> 6;          // 0..7
    const int bid   = blockIdx.x;
    const int group = bid & 3;
    const int jb    = bid >> 2;        // 0..31
    const int kg    = wave & 3;        // K-group (256 k each)
    const int ng    = wave >> 2;       // N-group (16 j each)

    __shared__ unsigned long long lds_h[4096];   // 32 KB staged h-slab
    __shared__ f32x4 part[8][3][64];             // 24 KB wave partials

    // ---- one-time: preload W_hh slice as MFMA B-fragments (96 VGPR) ----
    bf16x8 wf[8][3];
    #pragma unroll
    for (int kc = 0; kc < 8; ++kc) {
        #pragma unroll
        for (int nt = 0; nt < 3; ++nt) {
            int rowg = nt * HH + jb * 32 + ng * 16 + (lane & 15);
            int k    = kg * 256 + kc * 32 + ((lane >> 4) << 3);
            const float4* src = reinterpret_cast<const float4*>(Whh + (size_t)rowg * HH + k);
            float4 f0 = src[0], f1 = src[1];
            bf16x8 w;
            w[0] = (short)f2b(f0.x); w[1] = (short)f2b(f0.y);
            w[2] = (short)f2b(f0.z); w[3] = (short)f2b(f0.w);
            w[4] = (short)f2b(f1.x); w[5] = (short)f2b(f1.y);
            w[6] = (short)f2b(f1.z); w[7] = (short)f2b(f1.w);
            wf[kc][nt] = w;
        }
    }

    const int b_l = t >> 5;            // 0..15 local batch
    const int j_l = t & 31;            // 0..31 local j
    const int b_g = (group << 4) + b_l;
    const int j_g = (jb << 5) + j_l;
    float hreg = h0[b_g * HH + j_g];

    // A-fragment LDS byte base (add kc*1024 per chunk)
    const int frag_base = (kg * 32 + (lane >> 4)) * 256 + ((lane & 15) << 4);
    // publish byte offset within slab (even-j threads store packed pairs)
    const int prod_off  = ((j_g >> 3) << 8) + (b_l << 4) + ((j_g & 7) << 1);

    for (int s = 0; s < SS; ++s) {
        const int p = s & 1;
        const unsigned long long* rq =
            (const unsigned long long*)(h16 + (size_t)p * 65536 + group * 16384);
        unsigned short* wslab = h16 + (size_t)(p ^ 1) * 65536 + group * 16384;

        // prefetch gi (independent of h — issues before the poll)
        size_t gib = ((size_t)b_g * SS + s) * G3;
        float ir, iz, inn;
        if (GI_BF16) {
            const unsigned short* g16 = (const unsigned short*)gi_v;
            ir  = b2f(g16[gib + j_g]);
            iz  = b2f(g16[gib + HH + j_g]);
            inn = b2f(g16[gib + 2 * HH + j_g]);
        } else {
            const float* g32 = (const float*)gi_v;
            ir  = g32[gib + j_g];
            iz  = g32[gib + HH + j_g];
            inn = g32[gib + 2 * HH + j_g];
        }

        // wait until all 32 blocks of this group finished step s-1
        if (s > 0) {
            if (wave == 0) {
                const int fi = ((group << 5) | (lane & 31)) << 4;  // 64B stride
                while (true) {
                    int v = __hip_atomic_load(&flags[fi], __ATOMIC_RELAXED,
                                              __HIP_MEMORY_SCOPE_AGENT);
                    if (__all(v >= s)) break;
                    __builtin_amdgcn_s_sleep(1);
                }
                asm volatile("" ::: "memory");
            }
            __syncthreads();
        }

        // ---- stage the 32KB slab to LDS: 8x 8B sc1 loads per thread,
        //      each wave covers contiguous 512B segments ----
        unsigned long long sv[8];
        #pragma unroll
        for (int i = 0; i < 8; ++i)
            sv[i] = __hip_atomic_load(rq + i * 512 + t, __ATOMIC_RELAXED,
                                      __HIP_MEMORY_SCOPE_AGENT);
        #pragma unroll
        for (int i = 0; i < 8; ++i)
            lds_h[i * 512 + t] = sv[i];
        __syncthreads();

        // ---- gh partials: M=16, N=48 (3 gates x 16 j), K=256 per wave ----
        f32x4 a0 = {0,0,0,0}, a1 = {0,0,0,0}, a2 = {0,0,0,0};
        #pragma unroll
        for (int kc = 0; kc < 8; ++kc) {
            bf16x8 af = *reinterpret_cast<const bf16x8*>(
                (const char*)lds_h + frag_base + kc * 1024);
            a0 = __builtin_amdgcn_mfma_f32_16x16x32_bf16(af, wf[kc][0], a0, 0, 0, 0);
            a1 = __builtin_amdgcn_mfma_f32_16x16x32_bf16(af, wf[kc][1], a1, 0, 0, 0);
            a2 = __builtin_amdgcn_mfma_f32_16x16x32_bf16(af, wf[kc][2], a2, 0, 0, 0);
        }
        part[wave][0][lane] = a0;
        part[wave][1][lane] = a1;
        part[wave][2][lane] = a2;
        __syncthreads();

        // ---- cross-wave K reduce merged with gates: thread owns (b_l, j_l) ----
        const int ngr = j_l >> 4;
        const int lp  = ((b_l >> 2) << 4) | (j_l & 15);
        const int e   = b_l & 3;
        float hr = 0.f, hz = 0.f, hn = 0.f;
        #pragma unroll
        for (int k2 = 0; k2 < 4; ++k2) {
            hr += part[ngr * 4 + k2][0][lp][e];
            hz += part[ngr * 4 + k2][1][lp][e];
            hn += part[ngr * 4 + k2][2][lp][e];
        }

        // fast gates: sigmoid/tanh via v_exp + v_rcp (saturate correctly)
        float r  = __builtin_amdgcn_rcpf(1.f + __expf(-(ir + hr)));
        float z  = __builtin_amdgcn_rcpf(1.f + __expf(-(iz + hz)));
        float e2 = __expf(2.f * (inn + r * hn));
        float n  = 1.f - 2.f * __builtin_amdgcn_rcpf(e2 + 1.f);
        float hnew = (1.f - z) * n + z * hreg;
        hreg = hnew;

        // ---- publish h (packed bf16 pair, relaxed agent / sc1) ----
        unsigned short myb = f2b(hnew);
        unsigned pv = (unsigned)__shfl_xor((int)(unsigned)myb, 1);
        if (!(j_l & 1)) {
            unsigned val = ((unsigned)myb) | (pv << 16);
            __hip_atomic_store((unsigned*)((char*)wslab + prod_off), val,
                               __ATOMIC_RELAXED, __HIP_MEMORY_SCOPE_AGENT);
        }

        // release: drain sc1 stores to coherence point, then one flag store
        asm volatile("s_waitcnt vmcnt(0)" ::: "memory");
        __syncthreads();
        if (t == 0)
            __hip_atomic_store(&flags[((group << 5) | jb) << 4], s + 1,
                               __ATOMIC_RELAXED, __HIP_MEMORY_SCOPE_AGENT);

        // out store AFTER the release — not part of the recurrence
        out[((size_t)b_g * SS + s) * HH + j_g] = hnew;
    }

    out[(size_t)BB * SS * HH + (size_t)b_g * HH + j_g] = hreg;
}

// ---------------------------------------------------------------------------
// Host launcher
// ---------------------------------------------------------------------------
extern "C" void kernel_launch(void* const* d_in, const int* in_sizes, int n_in,
                              void* d_out, int out_size, void* d_ws, size_t ws_size,
                              hipStream_t stream)
{
    const float* x   = (const float*)d_in[0];
    const float* h0  = (const float*)d_in[1];
    const float* Wih = (const float*)d_in[2];
    const float* Whh = (const float*)d_in[3];
    const float* bih = (const float*)d_in[4];
    float* out = (float*)d_out;

    char* ws = (char*)d_ws;
    unsigned short* h16 = (unsigned short*)ws;               // 2 x 128KiB parity bufs
    int* flags          = (int*)(ws + 262144);               // 128 flags @ 64B stride
    void* gi            = (void*)(ws + (1 << 20));           // 1 MiB offset

    const size_t gi32_bytes = (size_t)BB * SS * G3 * 4;      // 768 MiB
    const size_t gi16_bytes = gi32_bytes / 2;                // 384 MiB
    const bool use_f32 = ws_size >= ((size_t)(1 << 20) + gi32_bytes);
    const bool use_b16 = !use_f32 && ws_size >= ((size_t)(1 << 20) + gi16_bytes);
    if (!use_f32 && !use_b16) return;

    gru_init<<<dim3(256), dim3(256), 0, stream>>>(h0, h16, flags);

    const void* gi_c = gi;
    const float* Whh_c = Whh;
    const float* h0_c = h0;
    unsigned short* h16_c = h16;
    int* flags_c = flags;
    float* out_c = out;
    void* args[] = { (void*)&gi_c, (void*)&Whh_c, (void*)&h0_c,
                     (void*)&h16_c, (void*)&flags_c, (void*)&out_c };

    if (use_f32) {
        gi_gemm<0><<<dim3(24, 512), dim3(256), 0, stream>>>(x, Wih, bih, gi);
        hipLaunchCooperativeKernel((const void*)&gru_scan<0>, dim3(128), dim3(512),
                                   args, 0, stream);
    } else {
        gi_gemm<1><<<dim3(24, 512), dim3(256), 0, stream>>>(x, Wih, bih, gi);
        hipLaunchCooperativeKernel((const void*)&gru_scan<1>, dim3(128), dim3(512),
                                   args, 0, stream);
    }
}

// Round 5
// 4244.936 us; speedup vs baseline: 2.6939x; 1.0309x over previous
//
#include <hip/hip_runtime.h>
#include <hip/hip_bf16.h>
#include <cstdint>
#include <cstddef>

// Problem sizes (fixed)
#define BB 64
#define SS 1024
#define II 1024
#define HH 1024
#define G3 3072   // 3*HH

typedef float  f32x4  __attribute__((ext_vector_type(4)));
typedef short  bf16x8 __attribute__((ext_vector_type(8)));

__device__ __forceinline__ unsigned short f2b(float f) {
    unsigned u = __float_as_uint(f);
    u += 0x7FFFu + ((u >> 16) & 1u);   // RNE
    return (unsigned short)(u >> 16);
}
__device__ __forceinline__ float b2f(unsigned short s) {
    return __uint_as_float(((unsigned)s) << 16);
}

// Interleaved h-slab layout (per 16-batch group, j = hidden index 0..1023):
//   elem offset F(b,j) = (j>>3)*128 + b*8 + (j&7)     (16K bf16 = 32KB slab)
// Wave w (K-slice [w*128,(w+1)*128)) chunk kc: lane reads 16B at byte
//   (w*16 + kc*4 + (l>>4))*256 + (l&15)*16  -> 1KB contiguous per (w,kc),
// and the 8 waves' ranges tile the slab exactly once (no duplicate reads).

// ---------------------------------------------------------------------------
// Kernel 1: gi = x @ W_ih^T + b_ih      (M=B*S=65536, K=1024, N=3072)
// ---------------------------------------------------------------------------
template<int GI_BF16>
__global__ __launch_bounds__(256)
void gi_gemm(const float* __restrict__ X, const float* __restrict__ W,
             const float* __restrict__ bias, void* __restrict__ gi_out)
{
    __shared__ short As[128][40];   // +8 pad breaks bank conflicts
    __shared__ short Bs[128][40];

    const int t    = threadIdx.x;
    const int lane = t & 63;
    const int wave = t >> 6;
    const int m0   = blockIdx.y * 128;
    const int n0   = blockIdx.x * 128;

    f32x4 acc[4][4] = {};

    for (int k0 = 0; k0 < II; k0 += 32) {
        __syncthreads();
        #pragma unroll
        for (int q = 0; q < 4; ++q) {
            int row = (t >> 3) + 32 * q;
            int col = (t & 7) * 4;
            const float4 a = *reinterpret_cast<const float4*>(X + (size_t)(m0 + row) * II + k0 + col);
            const float4 b = *reinterpret_cast<const float4*>(W + (size_t)(n0 + row) * II + k0 + col);
            As[row][col + 0] = (short)f2b(a.x); As[row][col + 1] = (short)f2b(a.y);
            As[row][col + 2] = (short)f2b(a.z); As[row][col + 3] = (short)f2b(a.w);
            Bs[row][col + 0] = (short)f2b(b.x); Bs[row][col + 1] = (short)f2b(b.y);
            Bs[row][col + 2] = (short)f2b(b.z); Bs[row][col + 3] = (short)f2b(b.w);
        }
        __syncthreads();

        const int mb = (wave & 1) * 64;
        const int nb = (wave >> 1) * 64;
        bf16x8 af[4], bf[4];
        #pragma unroll
        for (int i = 0; i < 4; ++i) {
            af[i] = *reinterpret_cast<const bf16x8*>(&As[mb + i * 16 + (lane & 15)][(lane >> 4) * 8]);
            bf[i] = *reinterpret_cast<const bf16x8*>(&Bs[nb + i * 16 + (lane & 15)][(lane >> 4) * 8]);
        }
        #pragma unroll
        for (int mi = 0; mi < 4; ++mi)
            #pragma unroll
            for (int ni = 0; ni < 4; ++ni)
                acc[mi][ni] = __builtin_amdgcn_mfma_f32_16x16x32_bf16(af[mi], bf[ni], acc[mi][ni], 0, 0, 0);
    }

    const int mb = (wave & 1) * 64;
    const int nb = (wave >> 1) * 64;
    #pragma unroll
    for (int ni = 0; ni < 4; ++ni) {
        int ncol = n0 + nb + ni * 16 + (lane & 15);
        float bv = bias[ncol];
        #pragma unroll
        for (int mi = 0; mi < 4; ++mi) {
            int mrow = m0 + mb + mi * 16 + ((lane >> 4) << 2);
            #pragma unroll
            for (int e = 0; e < 4; ++e) {
                float v = acc[mi][ni][e] + bv;
                size_t idx = (size_t)(mrow + e) * G3 + ncol;
                if (GI_BF16) ((unsigned short*)gi_out)[idx] = f2b(v);
                else         ((float*)gi_out)[idx] = v;
            }
        }
    }
}

// ---------------------------------------------------------------------------
// Kernel 2: init  (reset flags, h16[buf0] = bf16(h0) in interleaved layout)
// ---------------------------------------------------------------------------
__global__ __launch_bounds__(256)
void gru_init(const float* __restrict__ h0, unsigned short* __restrict__ h16,
              int* __restrict__ flags)
{
    int i = blockIdx.x * 256 + threadIdx.x;   // i = b*1024 + j, 65536 total
    int b = i >> 10, j = i & 1023;
    int dst = (b >> 4) * 16384 + (j >> 3) * 128 + (b & 15) * 8 + (j & 7);
    h16[dst] = f2b(h0[i]);
    if (i < 2048) flags[i] = 0;   // 128 flags at 16-int (64B) stride
}

// ---------------------------------------------------------------------------
// Kernel 3: sequential scan. Cooperative, 128 blocks x 512 threads (8 waves).
// group = bid&3 (16 batches), jb = bid>>2 (32 j-blocks of 32 j each).
// Wave w owns K-slice [w*128,(w+1)*128) x all 96 cols (3 gates x 32 j).
// Per step: all-wave flag poll -> direct sc1 reg loads of A-frags (no LDS
// staging) -> 24 MFMAs -> padded-LDS cross-wave K-reduce -> gates ->
// sc1 publish -> vmcnt(0) drain -> barrier -> flag. 2 barriers/step.
// NO cache-maintenance ops (acquire/buffer_inv) anywhere in the loop.
// ---------------------------------------------------------------------------
template<int GI_BF16>
__global__ __launch_bounds__(512, 1)
void gru_scan(const void* __restrict__ gi_v, const float* __restrict__ Whh,
              const float* __restrict__ h0, unsigned short* __restrict__ h16,
              int* __restrict__ flags, float* __restrict__ out)
{
    const int t     = threadIdx.x;
    const int lane  = t & 63;
    const int wave  = t >> 6;          // 0..7 = K-group (128 k each)
    const int bid   = blockIdx.x;
    const int group = bid & 3;
    const int jb    = bid >> 2;        // 0..31

    __shared__ float part[8][6][4][68];   // [wave][ntile][e][lane(+pad)] 52KB

    // ---- one-time: preload W_hh slice as MFMA B-fragments (96 VGPR) ----
    // nt = gate*2 + colHi: W row = gate*HH + jb*32 + colHi*16 + (lane&15)
    bf16x8 wf[4][6];
    #pragma unroll
    for (int kc = 0; kc < 4; ++kc) {
        #pragma unroll
        for (int nt = 0; nt < 6; ++nt) {
            int rowg = (nt >> 1) * HH + jb * 32 + (nt & 1) * 16 + (lane & 15);
            int k    = wave * 128 + kc * 32 + ((lane >> 4) << 3);
            const float4* src = reinterpret_cast<const float4*>(Whh + (size_t)rowg * HH + k);
            float4 f0 = src[0], f1 = src[1];
            bf16x8 w;
            w[0] = (short)f2b(f0.x); w[1] = (short)f2b(f0.y);
            w[2] = (short)f2b(f0.z); w[3] = (short)f2b(f0.w);
            w[4] = (short)f2b(f1.x); w[5] = (short)f2b(f1.y);
            w[6] = (short)f2b(f1.z); w[7] = (short)f2b(f1.w);
            wf[kc][nt] = w;
        }
    }

    const int b_l = t >> 5;            // 0..15 local batch
    const int j_l = t & 31;            // 0..31 local j
    const int b_g = (group << 4) + b_l;
    const int j_g = (jb << 5) + j_l;
    float hreg = h0[b_g * HH + j_g];

    // A-frag byte base within slab (add kc*1024 per chunk): wave-contiguous 1KB
    const int frag_base = (wave * 16 + (lane >> 4)) * 256 + ((lane & 15) << 4);
    // publish byte offset within slab (even-j threads store packed pairs)
    const int prod_off  = ((j_g >> 3) << 8) + (b_l << 4) + ((j_g & 7) << 1);

    // reduce-gather constants
    const int nt_r = j_l >> 4;                      // colHi
    const int lp   = ((b_l >> 2) << 4) | (j_l & 15);
    const int e_r  = b_l & 3;

    for (int s = 0; s < SS; ++s) {
        const int p = s & 1;
        const char* rslab = (const char*)(h16 + (size_t)p * 65536 + group * 16384);
        unsigned short* wslab = h16 + (size_t)(p ^ 1) * 65536 + group * 16384;

        // prefetch gi (independent of h — issues before the poll)
        size_t gib = ((size_t)b_g * SS + s) * G3;
        float ir, iz, inn;
        if (GI_BF16) {
            const unsigned short* g16 = (const unsigned short*)gi_v;
            ir  = b2f(g16[gib + j_g]);
            iz  = b2f(g16[gib + HH + j_g]);
            inn = b2f(g16[gib + 2 * HH + j_g]);
        } else {
            const float* g32 = (const float*)gi_v;
            ir  = g32[gib + j_g];
            iz  = g32[gib + HH + j_g];
            inn = g32[gib + 2 * HH + j_g];
        }

        // all-wave poll: wait until all 32 blocks of this group finished s-1.
        // Own block's flag is set only after the post-drain barrier of s-1, so
        // passing this poll also proves all local waves finished their gather.
        if (s > 0) {
            const int fi = ((group << 5) | (lane & 31)) << 4;  // 64B stride
            while (true) {
                int v = __hip_atomic_load(&flags[fi], __ATOMIC_RELAXED,
                                          __HIP_MEMORY_SCOPE_AGENT);
                if (__all(v >= s)) break;
                __builtin_amdgcn_s_sleep(1);
            }
            asm volatile("" ::: "memory");
        }

        // ---- A-fragments: direct sc1 loads to registers (2x u64 per chunk,
        //      1KB wave-contiguous per (wave,kc); slab read exactly once) ----
        unsigned long long hv[8];
        #pragma unroll
        for (int kc = 0; kc < 4; ++kc) {
            const unsigned long long* q =
                (const unsigned long long*)(rslab + frag_base + kc * 1024);
            hv[2 * kc]     = __hip_atomic_load(q,     __ATOMIC_RELAXED,
                                               __HIP_MEMORY_SCOPE_AGENT);
            hv[2 * kc + 1] = __hip_atomic_load(q + 1, __ATOMIC_RELAXED,
                                               __HIP_MEMORY_SCOPE_AGENT);
        }

        // ---- gh partials: M=16, N=96, K=128 per wave ----
        f32x4 acc[6] = {};
        #pragma unroll
        for (int kc = 0; kc < 4; ++kc) {
            union { unsigned long long q[2]; bf16x8 v; } u;
            u.q[0] = hv[2 * kc]; u.q[1] = hv[2 * kc + 1];
            #pragma unroll
            for (int nt = 0; nt < 6; ++nt)
                acc[nt] = __builtin_amdgcn_mfma_f32_16x16x32_bf16(u.v, wf[kc][nt], acc[nt], 0, 0, 0);
        }

        // scatter-store partials (lane-contiguous scalar stores: conflict-free)
        #pragma unroll
        for (int nt = 0; nt < 6; ++nt)
            #pragma unroll
            for (int e = 0; e < 4; ++e)
                part[wave][nt][e][lane] = acc[nt][e];
        __syncthreads();   // bar1

        // ---- cross-wave K reduce merged with gates (2-way banks: free) ----
        float hr = 0.f, hz = 0.f, hn = 0.f;
        #pragma unroll
        for (int w = 0; w < 8; ++w) {
            hr += part[w][0 + nt_r][e_r][lp];
            hz += part[w][2 + nt_r][e_r][lp];
            hn += part[w][4 + nt_r][e_r][lp];
        }

        // fast gates: sigmoid/tanh via v_exp + v_rcp (saturate correctly)
        float r  = __builtin_amdgcn_rcpf(1.f + __expf(-(ir + hr)));
        float z  = __builtin_amdgcn_rcpf(1.f + __expf(-(iz + hz)));
        float e2 = __expf(2.f * (inn + r * hn));
        float n  = 1.f - 2.f * __builtin_amdgcn_rcpf(e2 + 1.f);
        float hnew = (1.f - z) * n + z * hreg;
        hreg = hnew;

        // ---- publish h (packed bf16 pair, relaxed agent / sc1) ----
        unsigned short myb = f2b(hnew);
        unsigned pv = (unsigned)__shfl_xor((int)(unsigned)myb, 1);
        if (!(j_l & 1)) {
            unsigned val = ((unsigned)myb) | (pv << 16);
            __hip_atomic_store((unsigned*)((char*)wslab + prod_off), val,
                               __ATOMIC_RELAXED, __HIP_MEMORY_SCOPE_AGENT);
        }

        // release: per-wave drain of sc1 stores, barrier, then one flag store
        asm volatile("s_waitcnt vmcnt(0)" ::: "memory");
        __syncthreads();   // bar2 (also separates gather from next part store)
        if (t == 0)
            __hip_atomic_store(&flags[((group << 5) | jb) << 4], s + 1,
                               __ATOMIC_RELAXED, __HIP_MEMORY_SCOPE_AGENT);

        // out store AFTER the release — not part of the recurrence
        out[((size_t)b_g * SS + s) * HH + j_g] = hnew;
    }

    out[(size_t)BB * SS * HH + (size_t)b_g * HH + j_g] = hreg;
}

// ---------------------------------------------------------------------------
// Host launcher
// ---------------------------------------------------------------------------
extern "C" void kernel_launch(void* const* d_in, const int* in_sizes, int n_in,
                              void* d_out, int out_size, void* d_ws, size_t ws_size,
                              hipStream_t stream)
{
    const float* x   = (const float*)d_in[0];
    const float* h0  = (const float*)d_in[1];
    const float* Wih = (const float*)d_in[2];
    const float* Whh = (const float*)d_in[3];
    const float* bih = (const float*)d_in[4];
    float* out = (float*)d_out;

    char* ws = (char*)d_ws;
    unsigned short* h16 = (unsigned short*)ws;               // 2 x 128KiB parity bufs
    int* flags          = (int*)(ws + 262144);               // 128 flags @ 64B stride
    void* gi            = (void*)(ws + (1 << 20));           // 1 MiB offset

    const size_t gi32_bytes = (size_t)BB * SS * G3 * 4;      // 768 MiB
    const size_t gi16_bytes = gi32_bytes / 2;                // 384 MiB
    const bool use_f32 = ws_size >= ((size_t)(1 << 20) + gi32_bytes);
    const bool use_b16 = !use_f32 && ws_size >= ((size_t)(1 << 20) + gi16_bytes);
    if (!use_f32 && !use_b16) return;

    gru_init<<<dim3(256), dim3(256), 0, stream>>>(h0, h16, flags);

    const void* gi_c = gi;
    const float* Whh_c = Whh;
    const float* h0_c = h0;
    unsigned short* h16_c = h16;
    int* flags_c = flags;
    float* out_c = out;
    void* args[] = { (void*)&gi_c, (void*)&Whh_c, (void*)&h0_c,
                     (void*)&h16_c, (void*)&flags_c, (void*)&out_c };

    if (use_f32) {
        gi_gemm<0><<<dim3(24, 512), dim3(256), 0, stream>>>(x, Wih, bih, gi);
        hipLaunchCooperativeKernel((const void*)&gru_scan<0>, dim3(128), dim3(512),
                                   args, 0, stream);
    } else {
        gi_gemm<1><<<dim3(24, 512), dim3(256), 0, stream>>>(x, Wih, bih, gi);
        hipLaunchCooperativeKernel((const void*)&gru_scan<1>, dim3(128), dim3(512),
                                   args, 0, stream);
    }
}